// Round 1
// baseline (413.267 us; speedup 1.0000x reference)
//
#include <hip/hip_runtime.h>
#include <hip/hip_bf16.h>
#include <math.h>

typedef __bf16 bf16;
typedef __attribute__((ext_vector_type(8))) __bf16 bf16x8;
typedef __attribute__((ext_vector_type(4))) __bf16 bf16x4;
typedef __attribute__((ext_vector_type(4))) float f32x4;

enum { EPI_PLAIN = 0, EPI_GELU = 1, EPI_RES = 2, EPI_GATE = 3 };

__device__ __forceinline__ void async16(const void* g, void* l) {
  __builtin_amdgcn_global_load_lds(
      (const __attribute__((address_space(1))) void*)g,
      (__attribute__((address_space(3))) void*)l, 16, 0, 0);
}

__device__ __forceinline__ void bar() {
  asm volatile("" ::: "memory");
  __builtin_amdgcn_s_barrier();
  asm volatile("" ::: "memory");
}

#define WAIT_VM(n) asm volatile("s_waitcnt vmcnt(" #n ")" ::: "memory")
#define MFMA16(d, va, vb) \
  d = __builtin_amdgcn_mfma_f32_16x16x32_bf16(va, vb, d, 0, 0, 0)

// ---------------------------------------------------------------------------
// 256x256 tile, BK=64, 8 waves (2M x 4N), per-wave 128x64 output.
// LDS: ring of 4 half-slots per operand: slot = (tile&1)*2 + ksub, each
// [256 rows][32 k] bf16 = 16 KB. Total 4*16KB*2 = 128 KB.
// Swizzle (T2): within a row (4 chunks of 16B), chunk slot = q ^ ((r>>1)&3).
// Applied identically (involution) to global source (staging) and ds_read
// address; LDS dest stays linear for global_load_lds (rule #21).
// Schedule per K-tile t (4 phases, 16 MFMA each, 2 barriers/phase):
//   P0: read A[0..3]k0 + B[*]k0   ; stage Ak0(t+1)
//   P1: read A[4..7]k0            ; stage Bk0(t+1) ; vmcnt(4) [k1(t) landed]
//   P2: read A[0..3]k1 + B[*]k1   ; stage Ak1(t+1)
//   P3: read A[4..7]k1            ; stage Bk1(t+1) ; vmcnt(4) [k0(t+1) landed]
// Every stage targets a slot whose previous occupant's reads finished >=2
// barriers earlier (ledger in session notes); vmcnt never 0 except tail.
// ---------------------------------------------------------------------------
template <typename CT, int EPI>
__global__ __launch_bounds__(512, 2) void gemm256(
    const bf16* __restrict__ A, const bf16* __restrict__ B, CT* __restrict__ C,
    const float* __restrict__ bias, const bf16* __restrict__ resid,
    const float* __restrict__ sup, const float* __restrict__ wsg,
    const float* __restrict__ bsg, int M, int N, int K) {
  __shared__ bf16 As[4][8192];
  __shared__ bf16 Bs[4][8192];

  const int tid = threadIdx.x;
  const int bm = blockIdx.x, bn = blockIdx.y;
  const int lane = tid & 63, wv = tid >> 6;
  const int wm = wv >> 2, wn = wv & 3;  // 2 x 4 waves
  const int quad = lane >> 4, l16 = lane & 15;

  // ds_read side: element offset of swizzled 16B slot within a row
  const int slot8 = (quad ^ ((l16 >> 1) & 3)) * 8;
  const int offA = (wm * 128 + l16) * 32 + slot8;  // + i*512 per 16-row frag
  const int offB = (wn * 64 + l16) * 32 + slot8;   // + j*512 per 16-col frag

  // staging side: thread handles chunks c0=tid (rows 0..127) and c1=tid+512
  // (rows 128..255); global quad pre-swizzled with the same involution.
  const int r0 = tid >> 2;
  const int q8 = ((tid & 3) ^ ((r0 >> 1) & 3)) * 8;
  const bf16* pA0 = A + (size_t)(bm * 256 + r0) * K + q8;
  const bf16* pA1 = A + (size_t)(bm * 256 + r0 + 128) * K + q8;
  const bf16* pB0 = B + (size_t)(bn * 256 + r0) * K + q8;
  const bf16* pB1 = B + (size_t)(bn * 256 + r0 + 128) * K + q8;
  // per-wave linear LDS bases (hardware adds lane*16B)
  bf16* lA0 = &As[0][0] + wv * 512;
  bf16* lA1 = &As[0][0] + 4096 + wv * 512;
  bf16* lB0 = &Bs[0][0] + wv * 512;
  bf16* lB1 = &Bs[0][0] + 4096 + wv * 512;

  auto stA = [&](int s, int col) {
    async16(pA0 + col, lA0 + s * 8192);
    async16(pA1 + col, lA1 + s * 8192);
  };
  auto stB = [&](int s, int col) {
    async16(pB0 + col, lB0 + s * 8192);
    async16(pB1 + col, lB1 + s * 8192);
  };
  auto ldA = [&](int s, int i) {
    return *(const bf16x8*)(&As[s][offA + i * 512]);
  };
  auto ldB = [&](int s, int j) {
    return *(const bf16x8*)(&Bs[s][offB + j * 512]);
  };

  f32x4 acc[8][4];
#pragma unroll
  for (int i = 0; i < 8; i++)
#pragma unroll
    for (int j = 0; j < 4; j++) acc[i][j] = f32x4{0.f, 0.f, 0.f, 0.f};

  // prologue: tile 0 (ring 0), both k-halves; drain first 4 (Ak0,Bk0)
  stA(0, 0);
  stB(0, 0);
  stA(1, 32);
  stB(1, 32);
  WAIT_VM(4);
  bar();

  const int nt = K >> 6;
  for (int t = 0; t < nt; ++t) {
    const int s0 = (t & 1) * 2, s1 = s0 + 1;  // this tile's slots
    const int n0 = 2 - s0, n1 = n0 + 1;       // next tile's slots
    const bool st = (t + 1) < nt;
    const int ncol = (t + 1) * 64;
    bf16x8 a[4], b[4];

    // ---- P0 ----
#pragma unroll
    for (int i = 0; i < 4; i++) a[i] = ldA(s0, i);
#pragma unroll
    for (int j = 0; j < 4; j++) b[j] = ldB(s0, j);
    if (st) stA(n0, ncol);
    bar();
    __builtin_amdgcn_s_setprio(1);
#pragma unroll
    for (int i = 0; i < 4; i++)
#pragma unroll
      for (int j = 0; j < 4; j++) MFMA16(acc[i][j], a[i], b[j]);
    __builtin_amdgcn_s_setprio(0);
    bar();

    // ---- P1 ----
#pragma unroll
    for (int i = 0; i < 4; i++) a[i] = ldA(s0, i + 4);
    if (st) stB(n0, ncol);
    bar();
    __builtin_amdgcn_s_setprio(1);
#pragma unroll
    for (int i = 0; i < 4; i++)
#pragma unroll
      for (int j = 0; j < 4; j++) MFMA16(acc[i + 4][j], a[i], b[j]);
    __builtin_amdgcn_s_setprio(0);
    if (st) {
      WAIT_VM(4);  // k1(t) landed; 4 newest (k0/k?(t+1)) stay in flight
    } else {
      WAIT_VM(0);  // tail: drain k1(nt-1)
    }
    bar();

    // ---- P2 ----
#pragma unroll
    for (int i = 0; i < 4; i++) a[i] = ldA(s1, i);
#pragma unroll
    for (int j = 0; j < 4; j++) b[j] = ldB(s1, j);
    if (st) stA(n1, ncol + 32);
    bar();
    __builtin_amdgcn_s_setprio(1);
#pragma unroll
    for (int i = 0; i < 4; i++)
#pragma unroll
      for (int j = 0; j < 4; j++) MFMA16(acc[i][j], a[i], b[j]);
    __builtin_amdgcn_s_setprio(0);
    bar();

    // ---- P3 ----
#pragma unroll
    for (int i = 0; i < 4; i++) a[i] = ldA(s1, i + 4);
    if (st) stB(n1, ncol + 32);
    bar();
    __builtin_amdgcn_s_setprio(1);
#pragma unroll
    for (int i = 0; i < 4; i++)
#pragma unroll
      for (int j = 0; j < 4; j++) MFMA16(acc[i + 4][j], a[i], b[j]);
    __builtin_amdgcn_s_setprio(0);
    if (st) WAIT_VM(4);  // k0(t+1) landed; k1(t+1) stays in flight
    bar();
  }

  // ---- epilogue ----
#pragma unroll
  for (int i = 0; i < 8; i++) {
    const int row0 = bm * 256 + wm * 128 + i * 16 + quad * 4;
#pragma unroll
    for (int j = 0; j < 4; j++) {
      const int col = bn * 256 + wn * 64 + j * 16 + l16;
#pragma unroll
      for (int r = 0; r < 4; r++) {
        const int row = row0 + r;
        const size_t idx = (size_t)row * N + col;
        float v = acc[i][j][r];
        if constexpr (EPI == EPI_PLAIN) {
          C[idx] = (CT)v;
        } else if constexpr (EPI == EPI_GELU) {
          v += bias[col];
          float gl = 0.5f * v * (1.0f + erff(v * 0.70710678118654752f));
          C[idx] = (CT)gl;
        } else if constexpr (EPI == EPI_RES) {
          v += bias[col] + (float)resid[idx];
          C[idx] = (CT)v;
        } else {  // EPI_GATE
          v += bias[col];
          float g1 = 1.0f / (1.0f + expf(-v));
          float z = sup[row] * wsg[col] + bsg[col];
          float g2 = 1.0f / (1.0f + expf(-z));
          C[idx] = (CT)(g1 * g2);
        }
      }
    }
  }
}

// ---------------- chunked parallel scan ----------------
constexpr int SC_CH = 32, SC_NCH = 16, SC_CW = 32;

__global__ __launch_bounds__(512) void scan2_kernel(const float* __restrict__ g,
                                                    const bf16* __restrict__ xt,
                                                    bf16* __restrict__ s, int T, int C) {
  __shared__ float lA[SC_NCH][SC_CW];
  __shared__ float lB[SC_NCH][SC_CW];
  __shared__ float lC[SC_NCH][SC_CW];
  const int cl = threadIdx.x & (SC_CW - 1);
  const int ch = threadIdx.x / SC_CW;
  const int c = blockIdx.x * SC_CW + cl;
  const int n = blockIdx.y;
  const size_t base = ((size_t)n * T + ch * SC_CH) * C + c;

  float a_arr[SC_CH], sl[SC_CH];
  float A = 1.f, B = 0.f;
#pragma unroll
  for (int t = 0; t < SC_CH; ++t) {
    size_t idx = base + (size_t)t * C;
    float gv = g[idx], xv = (float)xt[idx];
    float at = 1.0f - gv;
    a_arr[t] = at;
    B = at * B + gv * xv;
    sl[t] = B;
    A *= at;
  }
  lA[ch][cl] = A;
  lB[ch][cl] = B;
  __syncthreads();
  if (ch == 0) {
    float carry = 0.f;
#pragma unroll
    for (int j = 0; j < SC_NCH; ++j) {
      lC[j][cl] = carry;
      carry = lA[j][cl] * carry + lB[j][cl];
    }
  }
  __syncthreads();
  const float carry = lC[ch][cl];
  float P = 1.f;
#pragma unroll
  for (int t = 0; t < SC_CH; ++t) {
    P *= a_arr[t];
    s[base + (size_t)t * C] = (bf16)(sl[t] + P * carry);
  }
}

// ---------------- weight converts (fused 5-way, scalar) ----------------
__global__ __launch_bounds__(256) void cvt5_kernel(
    const float* s0, bf16* d0, int n0, const float* s1, bf16* d1, int n1,
    const float* s2, bf16* d2, int n2, const float* s3, bf16* d3, int n3,
    const float* s4, bf16* d4, int n4) {
  const float* s; bf16* d; int n;
  switch (blockIdx.y) {
    case 0: s = s0; d = d0; n = n0; break;
    case 1: s = s1; d = d1; n = n1; break;
    case 2: s = s2; d = d2; n = n2; break;
    case 3: s = s3; d = d3; n = n3; break;
    default: s = s4; d = d4; n = n4; break;
  }
  int i = blockIdx.x * 256 + threadIdx.x;
  if (i < n) d[i] = (bf16)s[i];
}

// ---------------- vectorized fp32 -> bf16 (x_seq), n % 4 == 0 ----------------
__global__ __launch_bounds__(256) void cvtx_kernel(const float* __restrict__ in,
                                                   bf16* __restrict__ out, int n4) {
  int i = blockIdx.x * 256 + threadIdx.x;
  if (i < n4) {
    f32x4 v = *(const f32x4*)(in + (size_t)i * 4);
    bf16x4 b;
    b[0] = (bf16)v[0]; b[1] = (bf16)v[1]; b[2] = (bf16)v[2]; b[3] = (bf16)v[3];
    *(bf16x4*)(out + (size_t)i * 4) = b;
  }
}

extern "C" void kernel_launch(void* const* d_in, const int* in_sizes, int n_in,
                              void* d_out, int out_size, void* d_ws, size_t ws_size,
                              hipStream_t stream) {
  const float* x_seq = (const float*)d_in[0];
  const float* sup = (const float*)d_in[1];
  const float* W_in = (const float*)d_in[2];
  const float* W_out = (const float*)d_in[3];
  const float* W_bg = (const float*)d_in[4];
  const float* b_bg = (const float*)d_in[5];
  const float* W_sg = (const float*)d_in[6];
  const float* b_sg = (const float*)d_in[7];
  const float* W_f1 = (const float*)d_in[8];
  const float* b_f1 = (const float*)d_in[9];
  const float* W_f2 = (const float*)d_in[10];
  const float* b_f2 = (const float*)d_in[11];

  const int Nb = 32, T = 512, C = 768, H = 1536;
  const int M = Nb * T;  // 16384

  char* ws = (char*)d_ws;
  size_t off = 0;
  auto alloc = [&](size_t bytes) {
    void* p = ws + off;
    off += (bytes + 255) & ~(size_t)255;
    return p;
  };
  bf16* Win_bf = (bf16*)alloc((size_t)C * C * 2);
  bf16* Wf1_bf = (bf16*)alloc((size_t)H * C * 2);
  bf16* Wf2_bf = (bf16*)alloc((size_t)C * H * 2);
  bf16* Wbg_bf = (bf16*)alloc((size_t)C * C * 2);
  bf16* Wout_bf = (bf16*)alloc((size_t)C * C * 2);
  bf16* xs_bf = (bf16*)alloc((size_t)M * C * 2);  // x_seq bf16
  bf16* x_bf = (bf16*)alloc((size_t)M * C * 2);   // x; reused as s after G3
  bf16* h_bf = (bf16*)alloc((size_t)M * H * 2);
  bf16* xt_bf = (bf16*)alloc((size_t)M * C * 2);
  float* g_f = (float*)alloc((size_t)M * C * 4);
  bf16* s_bf = x_bf;  // x dead after G3

  cvt5_kernel<<<dim3((H * C + 255) / 256, 5), 256, 0, stream>>>(
      W_in, Win_bf, C * C, W_f1, Wf1_bf, H * C, W_f2, Wf2_bf, C * H,
      W_bg, Wbg_bf, C * C, W_out, Wout_bf, C * C);
  cvtx_kernel<<<(M * C / 4 + 255) / 256, 256, 0, stream>>>(x_seq, xs_bf, M * C / 4);

  dim3 blk(512);
  // G1: x = x_seq @ W_in^T
  gemm256<bf16, EPI_PLAIN><<<dim3(M / 256, C / 256), blk, 0, stream>>>(
      xs_bf, Win_bf, x_bf, nullptr, nullptr, nullptr, nullptr, nullptr, M, C, C);
  // G2: h = gelu(x @ W_f1^T + b_f1)
  gemm256<bf16, EPI_GELU><<<dim3(M / 256, H / 256), blk, 0, stream>>>(
      x_bf, Wf1_bf, h_bf, b_f1, nullptr, nullptr, nullptr, nullptr, M, H, C);
  // G3: xt = x + h @ W_f2^T + b_f2
  gemm256<bf16, EPI_RES><<<dim3(M / 256, C / 256), blk, 0, stream>>>(
      h_bf, Wf2_bf, xt_bf, b_f2, x_bf, nullptr, nullptr, nullptr, M, C, H);
  // G4: g = sigmoid(xt @ W_bg^T + b_bg) * sigmoid(sup*W_sg + b_sg)  (fp32 out)
  gemm256<float, EPI_GATE><<<dim3(M / 256, C / 256), blk, 0, stream>>>(
      xt_bf, Wbg_bf, g_f, b_bg, nullptr, sup, W_sg, b_sg, M, C, C);
  // scan
  scan2_kernel<<<dim3(C / SC_CW, Nb), dim3(SC_CW * SC_NCH), 0, stream>>>(
      g_f, xt_bf, s_bf, T, C);
  // G6: out = s @ W_out^T (fp32 out)
  gemm256<float, EPI_PLAIN><<<dim3(M / 256, C / 256), blk, 0, stream>>>(
      s_bf, Wout_bf, (float*)d_out, nullptr, nullptr, nullptr, nullptr, nullptr, M, C, C);
}

// Round 2
// 375.931 us; speedup vs baseline: 1.0993x; 1.0993x over previous
//
#include <hip/hip_runtime.h>
#include <hip/hip_bf16.h>
#include <math.h>

typedef __bf16 bf16;
typedef __attribute__((ext_vector_type(8))) __bf16 bf16x8;
typedef __attribute__((ext_vector_type(4))) __bf16 bf16x4;
typedef __attribute__((ext_vector_type(4))) float f32x4;

constexpr int BM = 128, BN = 128, BK = 32;

enum { EPI_PLAIN = 0, EPI_GELU = 1, EPI_RES = 2, EPI_GATE = 3 };

__device__ __forceinline__ void async16(const void* g, void* l) {
  __builtin_amdgcn_global_load_lds(
      (const __attribute__((address_space(1))) void*)g,
      (__attribute__((address_space(3))) void*)l, 16, 0, 0);
}

// barrier that drains LDS ops but NOT the global_load_lds prefetch queue
// (vmcnt stays counted -> loads remain in flight across the barrier).
// lgkmcnt(0) before s_barrier closes the "MFMA sunk past barrier while
// ds_read outstanding" hazard (rule #18) without costing the pipeline.
__device__ __forceinline__ void bar_lgkm() {
  asm volatile("s_waitcnt lgkmcnt(0)\n\ts_barrier" ::: "memory");
}

#define WAIT_VM(n) asm volatile("s_waitcnt vmcnt(" #n ")" ::: "memory")
#define MFMA16(d, va, vb) \
  d = __builtin_amdgcn_mfma_f32_16x16x32_bf16(va, vb, d, 0, 0, 0)

// ---------------------------------------------------------------------------
// bf16 GEMM, C = A[M,K] @ B[N,K]^T + epilogue.
// Round-0 structure (128x128 tile, 4 waves, [128][32] LDS tiles, 16 KB each)
// upgraded with:
//  (a) double-buffered LDS + prefetch: stage(t+1) issued BEFORE compute(t);
//      WAIT_VM(4) counted (the 4 newest loads = stage(t+1) stay in flight
//      across both barriers) -> one full K-step of latency cover, no
//      vmcnt(0) drain in the main loop.
//  (b) XOR chunk swizzle (HW-verified in prev round: conflicts 4.7M -> 0):
//      LDS dest stays linear (global_load_lds requirement); the global
//      SOURCE chunk and the ds_read slot are permuted with the same
//      involution  chunk ^= (row>>1)&3  (row parity classes spread the
//      16B granules over all 8 bank-quads evenly).
// ---------------------------------------------------------------------------
template <typename CT, int EPI>
__global__ __launch_bounds__(256, 2) void gemm_bt_a(
    const bf16* __restrict__ A, const bf16* __restrict__ B, CT* __restrict__ C,
    const float* __restrict__ bias, const bf16* __restrict__ resid,
    const float* __restrict__ sup, const float* __restrict__ wsg,
    const float* __restrict__ bsg, int M, int N, int K) {
  __shared__ bf16 As[2][BM * BK];
  __shared__ bf16 Bs[2][BN * BK];

  const int tid = threadIdx.x;
  const int bm = blockIdx.x, bn = blockIdx.y;
  const int lane = tid & 63;
  const int wv = tid >> 6;
  const int wm = (wv >> 1) * 64, wn = (wv & 1) * 64;
  const int quad = lane >> 4, l16 = lane & 15;

  f32x4 acc[4][4];
#pragma unroll
  for (int i = 0; i < 4; i++)
#pragma unroll
    for (int j = 0; j < 4; j++) acc[i][j] = f32x4{0.f, 0.f, 0.f, 0.f};

  const bf16* Ab = A + (size_t)(bm * BM) * K;
  const bf16* Bb = B + (size_t)(bn * BN) * K;
  // staging: thread covers chunk (row=it*64+srow, pos=tid&3); source chunk
  // pre-swizzled by the involution so linear LDS + swizzled read matches.
  const int srow = tid >> 2;
  const int sq8 = ((tid & 3) ^ ((srow >> 1) & 3)) * 8;  // (it*64)%8==0 -> it-safe
  // read side: swizzled 16B slot within the 64B row
  const int slot8 = (quad ^ ((l16 >> 1) & 3)) * 8;      // rows wm+i*16+l16: parity from l16 only

  auto stage = [&](int buf, int kk) {
#pragma unroll
    for (int it = 0; it < 2; ++it) {
      int row = it * 64 + srow;
      async16(Ab + (size_t)row * K + kk + sq8, &As[buf][(it * 256 + wv * 64) * 8]);
    }
#pragma unroll
    for (int it = 0; it < 2; ++it) {
      int row = it * 64 + srow;
      async16(Bb + (size_t)row * K + kk + sq8, &Bs[buf][(it * 256 + wv * 64) * 8]);
    }
  };

  stage(0, 0);  // prologue: tile 0 in flight (4 loads/thread)

  const int nt = K / BK;
  for (int t = 0; t < nt; ++t) {
    const int cur = t & 1;
    if (t + 1 < nt) {
      stage(cur ^ 1, (t + 1) * BK);  // issue next tile FIRST (8 newest... 4 newest)
      WAIT_VM(4);                    // tile t landed; tile t+1 stays in flight
    } else {
      WAIT_VM(0);                    // tail: drain last tile
    }
    bar_lgkm();

    bf16x8 af[4], bfr[4];
#pragma unroll
    for (int i = 0; i < 4; i++)
      af[i] = *(const bf16x8*)&As[cur][(wm + i * 16 + l16) * BK + slot8];
#pragma unroll
    for (int j = 0; j < 4; j++)
      bfr[j] = *(const bf16x8*)&Bs[cur][(wn + j * 16 + l16) * BK + slot8];
#pragma unroll
    for (int i = 0; i < 4; i++)
#pragma unroll
      for (int j = 0; j < 4; j++)
        acc[i][j] = __builtin_amdgcn_mfma_f32_16x16x32_bf16(af[i], bfr[j], acc[i][j], 0, 0, 0);
    bar_lgkm();  // all waves done reading buf[cur] before next stage overwrites it
  }

#pragma unroll
  for (int i = 0; i < 4; i++) {
    int row0 = bm * BM + wm + i * 16 + quad * 4;
#pragma unroll
    for (int j = 0; j < 4; j++) {
      int col = bn * BN + wn + j * 16 + l16;
#pragma unroll
      for (int r = 0; r < 4; r++) {
        int row = row0 + r;
        size_t idx = (size_t)row * N + col;
        float v = acc[i][j][r];
        if constexpr (EPI == EPI_PLAIN) {
          C[idx] = (CT)v;
        } else if constexpr (EPI == EPI_GELU) {
          v += bias[col];
          float gl = 0.5f * v * (1.0f + erff(v * 0.70710678118654752f));
          C[idx] = (CT)gl;
        } else if constexpr (EPI == EPI_RES) {
          v += bias[col] + (float)resid[idx];
          C[idx] = (CT)v;
        } else {  // EPI_GATE
          v += bias[col];
          float g1 = 1.0f / (1.0f + expf(-v));
          float z = sup[row] * wsg[col] + bsg[col];
          float g2 = 1.0f / (1.0f + expf(-z));
          C[idx] = (CT)(g1 * g2);
        }
      }
    }
  }
}

// ---------------- chunked parallel scan ----------------
constexpr int SC_CH = 32, SC_NCH = 16, SC_CW = 32;

__global__ __launch_bounds__(512) void scan2_kernel(const float* __restrict__ g,
                                                    const bf16* __restrict__ xt,
                                                    bf16* __restrict__ s, int T, int C) {
  __shared__ float lA[SC_NCH][SC_CW];
  __shared__ float lB[SC_NCH][SC_CW];
  __shared__ float lC[SC_NCH][SC_CW];
  const int cl = threadIdx.x & (SC_CW - 1);
  const int ch = threadIdx.x / SC_CW;
  const int c = blockIdx.x * SC_CW + cl;
  const int n = blockIdx.y;
  const size_t base = ((size_t)n * T + ch * SC_CH) * C + c;

  float a_arr[SC_CH], sl[SC_CH];
  float A = 1.f, B = 0.f;
#pragma unroll
  for (int t = 0; t < SC_CH; ++t) {
    size_t idx = base + (size_t)t * C;
    float gv = g[idx], xv = (float)xt[idx];
    float at = 1.0f - gv;
    a_arr[t] = at;
    B = at * B + gv * xv;
    sl[t] = B;
    A *= at;
  }
  lA[ch][cl] = A;
  lB[ch][cl] = B;
  __syncthreads();
  if (ch == 0) {
    float carry = 0.f;
#pragma unroll
    for (int j = 0; j < SC_NCH; ++j) {
      lC[j][cl] = carry;
      carry = lA[j][cl] * carry + lB[j][cl];
    }
  }
  __syncthreads();
  const float carry = lC[ch][cl];
  float P = 1.f;
#pragma unroll
  for (int t = 0; t < SC_CH; ++t) {
    P *= a_arr[t];
    s[base + (size_t)t * C] = (bf16)(sl[t] + P * carry);
  }
}

// ---------------- weight converts (fused 5-way, scalar) ----------------
__global__ __launch_bounds__(256) void cvt5_kernel(
    const float* s0, bf16* d0, int n0, const float* s1, bf16* d1, int n1,
    const float* s2, bf16* d2, int n2, const float* s3, bf16* d3, int n3,
    const float* s4, bf16* d4, int n4) {
  const float* s; bf16* d; int n;
  switch (blockIdx.y) {
    case 0: s = s0; d = d0; n = n0; break;
    case 1: s = s1; d = d1; n = n1; break;
    case 2: s = s2; d = d2; n = n2; break;
    case 3: s = s3; d = d3; n = n3; break;
    default: s = s4; d = d4; n = n4; break;
  }
  int i = blockIdx.x * 256 + threadIdx.x;
  if (i < n) d[i] = (bf16)s[i];
}

// ---------------- vectorized fp32 -> bf16 (x_seq), n % 4 == 0 ----------------
__global__ __launch_bounds__(256) void cvtx_kernel(const float* __restrict__ in,
                                                   bf16* __restrict__ out, int n4) {
  int i = blockIdx.x * 256 + threadIdx.x;
  if (i < n4) {
    f32x4 v = *(const f32x4*)(in + (size_t)i * 4);
    bf16x4 b;
    b[0] = (bf16)v[0]; b[1] = (bf16)v[1]; b[2] = (bf16)v[2]; b[3] = (bf16)v[3];
    *(bf16x4*)(out + (size_t)i * 4) = b;
  }
}

extern "C" void kernel_launch(void* const* d_in, const int* in_sizes, int n_in,
                              void* d_out, int out_size, void* d_ws, size_t ws_size,
                              hipStream_t stream) {
  const float* x_seq = (const float*)d_in[0];
  const float* sup = (const float*)d_in[1];
  const float* W_in = (const float*)d_in[2];
  const float* W_out = (const float*)d_in[3];
  const float* W_bg = (const float*)d_in[4];
  const float* b_bg = (const float*)d_in[5];
  const float* W_sg = (const float*)d_in[6];
  const float* b_sg = (const float*)d_in[7];
  const float* W_f1 = (const float*)d_in[8];
  const float* b_f1 = (const float*)d_in[9];
  const float* W_f2 = (const float*)d_in[10];
  const float* b_f2 = (const float*)d_in[11];

  const int Nb = 32, T = 512, C = 768, H = 1536;
  const int M = Nb * T;  // 16384

  char* ws = (char*)d_ws;
  size_t off = 0;
  auto alloc = [&](size_t bytes) {
    void* p = ws + off;
    off += (bytes + 255) & ~(size_t)255;
    return p;
  };
  bf16* Win_bf = (bf16*)alloc((size_t)C * C * 2);
  bf16* Wf1_bf = (bf16*)alloc((size_t)H * C * 2);
  bf16* Wf2_bf = (bf16*)alloc((size_t)C * H * 2);
  bf16* Wbg_bf = (bf16*)alloc((size_t)C * C * 2);
  bf16* Wout_bf = (bf16*)alloc((size_t)C * C * 2);
  bf16* xs_bf = (bf16*)alloc((size_t)M * C * 2);  // x_seq bf16
  bf16* x_bf = (bf16*)alloc((size_t)M * C * 2);   // x; reused as s after G3
  bf16* h_bf = (bf16*)alloc((size_t)M * H * 2);
  bf16* xt_bf = (bf16*)alloc((size_t)M * C * 2);
  float* g_f = (float*)alloc((size_t)M * C * 4);
  bf16* s_bf = x_bf;  // x dead after G3

  cvt5_kernel<<<dim3((H * C + 255) / 256, 5), 256, 0, stream>>>(
      W_in, Win_bf, C * C, W_f1, Wf1_bf, H * C, W_f2, Wf2_bf, C * H,
      W_bg, Wbg_bf, C * C, W_out, Wout_bf, C * C);
  cvtx_kernel<<<(M * C / 4 + 255) / 256, 256, 0, stream>>>(x_seq, xs_bf, M * C / 4);

  dim3 blk(256);
  // G1: x = x_seq @ W_in^T
  gemm_bt_a<bf16, EPI_PLAIN><<<dim3(M / BM, C / BN), blk, 0, stream>>>(
      xs_bf, Win_bf, x_bf, nullptr, nullptr, nullptr, nullptr, nullptr, M, C, C);
  // G2: h = gelu(x @ W_f1^T + b_f1)
  gemm_bt_a<bf16, EPI_GELU><<<dim3(M / BM, H / BN), blk, 0, stream>>>(
      x_bf, Wf1_bf, h_bf, b_f1, nullptr, nullptr, nullptr, nullptr, M, H, C);
  // G3: xt = x + h @ W_f2^T + b_f2
  gemm_bt_a<bf16, EPI_RES><<<dim3(M / BM, C / BN), blk, 0, stream>>>(
      h_bf, Wf2_bf, xt_bf, b_f2, x_bf, nullptr, nullptr, nullptr, M, C, H);
  // G4: g = sigmoid(xt @ W_bg^T + b_bg) * sigmoid(sup*W_sg + b_sg)  (fp32 out)
  gemm_bt_a<float, EPI_GATE><<<dim3(M / BM, C / BN), blk, 0, stream>>>(
      xt_bf, Wbg_bf, g_f, b_bg, nullptr, sup, W_sg, b_sg, M, C, C);
  // scan
  scan2_kernel<<<dim3(C / SC_CW, Nb), dim3(SC_CW * SC_NCH), 0, stream>>>(
      g_f, xt_bf, s_bf, T, C);
  // G6: out = s @ W_out^T (fp32 out)
  gemm_bt_a<float, EPI_PLAIN><<<dim3(M / BM, C / BN), blk, 0, stream>>>(
      s_bf, Wout_bf, (float*)d_out, nullptr, nullptr, nullptr, nullptr, nullptr, M, C, C);
}